// Round 11
// baseline (128.249 us; speedup 1.0000x reference)
//
#include <hip/hip_runtime.h>
#include <cmath>

typedef float  f32x4  __attribute__((ext_vector_type(4)));
typedef __bf16 bf16x8 __attribute__((ext_vector_type(8)));
typedef unsigned int u32x4 __attribute__((ext_vector_type(4)));
typedef unsigned int   u32;
typedef unsigned short u16;

#define HEAD_DIM 64
#define N_HEADS  25
#define N_KV     5
#define WINDOW   1024
#define N_META   128
#define B_       2
#define T_       2048
#define QB       64                 // queries per block (2 waves x 32)
#define NTILES   (T_ / 64)          // 32 k-tiles per (b,kvh)
#define TILE_U32 2048               // 64 rows x 32 u32 (8 KB)

static __device__ __forceinline__ u16 bf16_bits(float f) {
  __bf16 h = (__bf16)f;
  return __builtin_bit_cast(u16, h);
}
static __device__ __forceinline__ u32 pack2(float lo, float hi) {
  return ((u32)bf16_bits(hi) << 16) | bf16_bits(lo);
}
static __device__ __forceinline__ void gload16(const u32* g, u32* l) {
  __builtin_amdgcn_global_load_lds((const __attribute__((address_space(1))) u32*)g,
                                   (__attribute__((address_space(3))) u32*)l, 16, 0, 0);
}

// ---------------- Kernel 1: K RMSNorm+RoPE -> bf16 tiles, seg-XOR pre-swizzled ----------
// [b][kvh][tile][key(64)][seg_phys(8) x 4 u32]; seg_phys = seg_log ^ (key&7)
__global__ __launch_bounds__(256) void prep_k_kernel(
    const float* __restrict__ k_in, const float* __restrict__ k_w,
    const int* __restrict__ pos_ids, u32* __restrict__ k_ws)
{
  int gw   = (blockIdx.x * blockDim.x + threadIdx.x) >> 6;
  int lane = threadIdx.x & 63;
  if (gw >= B_ * T_ * N_KV) return;
  int kvh = gw % N_KV;
  int bt  = gw / N_KV;

  float x = k_in[(size_t)bt * (N_KV * HEAD_DIM) + kvh * HEAD_DIM + lane];
  float ss = x * x;
  #pragma unroll
  for (int off = 32; off; off >>= 1) ss += __shfl_xor(ss, off);
  float y = k_w[lane] * x * rsqrtf(ss * (1.f / 64.f) + 1e-6f);

  int   pos = pos_ids[bt];
  float ang = (float)pos * powf(10000.f, -(float)(lane & 31) * (1.f / 32.f));
  float c, s;
  sincosf(ang, &s, &c);
  float part = __shfl_xor(y, 32);
  float r = (lane < 32) ? (y * c - part * s) : (y * c + part * s);

  u16 mybits = bf16_bits(r);
  u32 pb = (u32)(u16)__shfl_xor((int)mybits, 1);
  u32 w  = (pb << 16) | mybits;
  int b = bt / T_, t = bt % T_;
  if (!(lane & 1)) {
    int c32 = lane >> 1;
    int kl = t & 63, tile = t >> 6;
    int sp = (c32 >> 2) ^ (kl & 7);
    k_ws[(((size_t)(b * N_KV + kvh) * NTILES + tile)) * TILE_U32 + kl * 32 + sp * 4 + (c32 & 3)] = w;
  }
}

// ---------------- Kernel 1b: V -> bf16 V^T tiles, b128 K-group pre-swizzled ------------
// [b][kvh][tile][d(64)][32 u32]. Logical u32 col c holds keys (2c,2c+1). c = 16a+8b+2g+e
// stored at phys seg sp = (4a+g)^(d&7), slot 2b+e. Attn's b128 read at seg (4ks2+g)^(d&7)
// then yields keys {32ks2+4g+0..3, 32ks2+16+4g+0..3} = exactly the PV A-frag k-order.
__global__ __launch_bounds__(256) void prep_v_kernel(
    const float* __restrict__ v_in, u32* __restrict__ v_ws)
{
  int blk  = blockIdx.x;
  int tile = blk & (NTILES - 1);
  int bk   = blk >> 5;
  int kvh  = bk % N_KV, b = bk / N_KV;
  int t0   = tile * 64;
  int tid  = threadIdx.x;

  __shared__ u16 Tl[64][72];             // [d][key]

  #pragma unroll
  for (int it = 0; it < 4; ++it) {
    int idx = it * 256 + tid;
    int kl = idx >> 4, dq = idx & 15;
    const float4 f = *(const float4*)&v_in[((size_t)(b * T_ + t0 + kl)) * (N_KV * HEAD_DIM) + kvh * HEAD_DIM + dq * 4];
    Tl[dq * 4 + 0][kl] = bf16_bits(f.x);
    Tl[dq * 4 + 1][kl] = bf16_bits(f.y);
    Tl[dq * 4 + 2][kl] = bf16_bits(f.z);
    Tl[dq * 4 + 3][kl] = bf16_bits(f.w);
  }
  __syncthreads();

  u32* outb = v_ws + (size_t)blk * TILE_U32;
  #pragma unroll
  for (int it = 0; it < 8; ++it) {
    int o = it * 256 + tid;
    int d = o >> 5, c = o & 31;
    u32 w = ((u32)Tl[d][2 * c + 1] << 16) | Tl[d][2 * c];
    int a = c >> 4, bs = (c >> 3) & 1, gp = (c >> 1) & 3, e = c & 1;
    int sp = (4 * a + gp) ^ (d & 7);
    outb[d * 32 + sp * 4 + 2 * bs + e] = w;
  }
}

// ---------------- Kernel 2: fused MFMA flash attention ----------------
// 128-thread blocks (2 waves); QB=64; each wave owns 32 queries (2 q-frags).
// Each kf/vf LDS fragment feeds 2 MFMAs; 1600 blocks keep ~5 LDS-limited blocks/CU.
__global__ __launch_bounds__(128, 2) void attn_kernel(
    const float* __restrict__ q_in, const float* __restrict__ q_w,
    const int* __restrict__ pos_ids,
    const u32* __restrict__ kws, const u32* __restrict__ vws,
    float* __restrict__ out)
{
  const int blk = blockIdx.x;
  const int r   = blk / 50, v = blk % 50;          // heavy-first: qt descending
  const int qt  = 31 - r;
  const int h   = v % N_HEADS;
  const int b   = v / N_HEADS;
  const int qb  = qt * QB;
  const int kvh = h / (N_HEADS / N_KV);
  const int tid = threadIdx.x, wid = tid >> 6, lane = tid & 63;
  const int l15 = lane & 15, g = lane >> 4;
  const int qrow0 = wid * 32;                      // wave owns 32 queries

  __shared__ u32 Ks[2 * TILE_U32];       // K tiles (buf1 doubles as Q staging pre-loop)
  __shared__ u32 Vt[2 * TILE_U32];       // V^T tiles

  // tiles: {0,1} U [max(2, qt-16), qt]
  const int nt    = (qt <= 18) ? (qt + 1) : 19;
  const int shift = qt - 18;                       // only used when qt > 18

  const size_t kvbase = ((size_t)(b * N_KV + kvh)) * NTILES * TILE_U32;
  const u32* kb = kws + kvbase;
  const u32* vb = vws + kvbase;

  // ---- issue tile-0 staging first (hides under Q-staging compute) ----
  // wave0 loads all 8 K chunks, wave1 all 8 V chunks (1 KB each)
  #pragma unroll
  for (int j = 0; j < 8; ++j) {
    int ci = (wid << 3) | j;
    if (ci < 8) gload16(kb + ci * 256 + lane * 4, &Ks[ci * 256]);
    else        gload16(vb + (ci - 8) * 256 + lane * 4, &Vt[(ci - 8) * 256]);
  }

  // ---- Q staging (32 rows/wave) into Ks buf1: RMSNorm + RoPE (rotation recurrence) ----
  {
    const int lj = lane & 31;
    const float f = powf(10000.f, -(float)lj * (1.f / 32.f));
    const int t0 = qb + qrow0;
    int pos_prev = pos_ids[b * T_ + t0];
    float cc, sn;
    sincosf((float)pos_prev * f, &sn, &cc);        // sincosf(x, sin*, cos*)
    float sf, cf;
    sincosf(f, &sf, &cf);
    for (int rr = 0; rr < 32; ++rr) {
      int t = t0 + rr;
      if (rr) {
        int pos = pos_ids[b * T_ + t];
        if (pos == pos_prev + 1) {                 // wave-uniform fast path
          float c2 = cc * cf - sn * sf;
          sn = sn * cf + cc * sf;
          cc = c2;
        } else {
          sincosf((float)pos * f, &sn, &cc);
        }
        pos_prev = pos;
      }
      float x = q_in[((size_t)(b * T_ + t)) * (N_HEADS * HEAD_DIM) + h * HEAD_DIM + lane];
      float ss = x * x;
      #pragma unroll
      for (int off = 32; off; off >>= 1) ss += __shfl_xor(ss, off);
      float y = q_w[lane] * x * rsqrtf(ss * (1.f / 64.f) + 1e-6f);
      float part = __shfl_xor(y, 32);
      float rv = ((lane < 32) ? (y * cc - part * sn) : (y * cc + part * sn)) * 0.18033688f;
      u16 mybits = bf16_bits(rv);
      u32 pb = (u32)(u16)__shfl_xor((int)mybits, 1);
      if (!(lane & 1)) Ks[TILE_U32 + (qrow0 + rr) * 32 + (lane >> 1)] = (pb << 16) | mybits;
    }
  }
  __syncthreads();                       // tile0 loads drained + Q rows visible

  bf16x8 qf[2][2];                       // [qn][ks]
  #pragma unroll
  for (int qn = 0; qn < 2; ++qn)
    #pragma unroll
    for (int ks = 0; ks < 2; ++ks)
      qf[qn][ks] = *(const bf16x8*)&Ks[TILE_U32 + (qrow0 + 16 * qn + l15) * 32 + 16 * ks + 4 * g];
  __syncthreads();                       // qf reads done before buf1 is overwritten

  float m_reg[2] = {-INFINITY, -INFINITY};
  float l_part[2] = {0.f, 0.f};          // per-lane partial of l (g-reduce deferred)
  f32x4 acc_o[2][4];
  #pragma unroll
  for (int qn = 0; qn < 2; ++qn)
    #pragma unroll
    for (int mt = 0; mt < 4; ++mt) acc_o[qn][mt] = (f32x4)(0.f);

  const int q_abs0 = qb + qrow0 + l15;   // qn=0; qn=1 adds 16

  int buf = 0;
  for (int i = 0; i < nt; ++i) {
    // ---- prefetch next tile into buf^1 ----
    if (i + 1 < nt) {
      int tn = (qt <= 18 || i + 1 < 2) ? (i + 1) : (i + 1 + shift);
      const u32* kt = kb + (size_t)tn * TILE_U32;
      const u32* vt = vb + (size_t)tn * TILE_U32;
      u32* kd = &Ks[(buf ^ 1) * TILE_U32];
      u32* vd = &Vt[(buf ^ 1) * TILE_U32];
      #pragma unroll
      for (int j = 0; j < 8; ++j) {
        int ci = (wid << 3) | j;
        if (ci < 8) gload16(kt + ci * 256 + lane * 4, kd + ci * 256);
        else        gload16(vt + (ci - 8) * 256 + lane * 4, vd + (ci - 8) * 256);
      }
    }
    const int k0 = ((qt <= 18 || i < 2) ? i : i + shift) << 6;

    // ---- S^T = K·Q^T for both q-frags; each kf load feeds 2 MFMAs ----
    f32x4 accs[2][4];
    #pragma unroll
    for (int qn = 0; qn < 2; ++qn)
      #pragma unroll
      for (int mt = 0; mt < 4; ++mt) accs[qn][mt] = (f32x4)(0.f);
    #pragma unroll
    for (int ks = 0; ks < 2; ++ks) {
      #pragma unroll
      for (int mt = 0; mt < 4; ++mt) {
        bf16x8 kf = *(const bf16x8*)&Ks[buf * TILE_U32 + (16 * mt + l15) * 32 + (((4 * ks + g) ^ (l15 & 7)) << 2)];
        accs[0][mt] = __builtin_amdgcn_mfma_f32_16x16x32_bf16(kf, qf[0][ks], accs[0][mt], 0, 0, 0);
        accs[1][mt] = __builtin_amdgcn_mfma_f32_16x16x32_bf16(kf, qf[1][ks], accs[1][mt], 0, 0, 0);
      }
    }

    // ---- mask only on boundary tiles (diagonal; window-entry i==2 when qt>=18:
    //      at qt=18, window lower edge q-1023 lands inside tile 2 -> must mask) ----
    const bool do_mask = (i == nt - 1) || (qt >= 18 && i == 2);

    #pragma unroll
    for (int qn = 0; qn < 2; ++qn) {
      const int q_abs = q_abs0 + 16 * qn;
      float tmax = -INFINITY;
      if (do_mask) {
        #pragma unroll
        for (int mt = 0; mt < 4; ++mt)
          #pragma unroll
          for (int rg = 0; rg < 4; ++rg) {
            int key = k0 + 16 * mt + 4 * g + rg;
            bool ok = (key <= q_abs) && ((key >= q_abs - (WINDOW - 1)) || (key < N_META));
            float sv = ok ? accs[qn][mt][rg] : -INFINITY;
            accs[qn][mt][rg] = sv;
            tmax = fmaxf(tmax, sv);
          }
      } else {
        #pragma unroll
        for (int mt = 0; mt < 4; ++mt)
          #pragma unroll
          for (int rg = 0; rg < 4; ++rg) tmax = fmaxf(tmax, accs[qn][mt][rg]);
      }
      tmax = fmaxf(tmax, __shfl_xor(tmax, 16));
      tmax = fmaxf(tmax, __shfl_xor(tmax, 32));

      float mn = m_reg[qn];
      if (!__all(tmax <= mn)) {          // defer-max: skip rescale when no growth
        mn = fmaxf(mn, tmax);
        float scl = exp2f(m_reg[qn] - mn);
        m_reg[qn] = mn;
        l_part[qn] *= scl;
        float scl4[4];
        #pragma unroll
        for (int rg = 0; rg < 4; ++rg) scl4[rg] = __shfl(scl, 4 * g + rg);
        #pragma unroll
        for (int mt2 = 0; mt2 < 4; ++mt2)
          #pragma unroll
          for (int rg = 0; rg < 4; ++rg) acc_o[qn][mt2][rg] *= scl4[rg];
      }
      float rsum = 0.f;
      #pragma unroll
      for (int mt = 0; mt < 4; ++mt)
        #pragma unroll
        for (int rg = 0; rg < 4; ++rg) {
          float pi = exp2f(accs[qn][mt][rg] - mn);
          accs[qn][mt][rg] = pi;
          rsum += pi;
        }
      l_part[qn] += rsum;                // per-lane partial; g-reduce in epilogue
    }

    // ---- O += P·V; each vf load feeds 2 MFMAs ----
    #pragma unroll
    for (int ks2 = 0; ks2 < 2; ++ks2) {
      const int m0 = 2 * ks2, m1 = 2 * ks2 + 1;
      bf16x8 af[2];
      #pragma unroll
      for (int qn = 0; qn < 2; ++qn) {
        u32x4 aw;
        aw.x = pack2(accs[qn][m0][0], accs[qn][m0][1]);
        aw.y = pack2(accs[qn][m0][2], accs[qn][m0][3]);
        aw.z = pack2(accs[qn][m1][0], accs[qn][m1][1]);
        aw.w = pack2(accs[qn][m1][2], accs[qn][m1][3]);
        af[qn] = __builtin_bit_cast(bf16x8, aw);
      }
      #pragma unroll
      for (int mt2 = 0; mt2 < 4; ++mt2) {
        bf16x8 vf = *(const bf16x8*)&Vt[buf * TILE_U32 + (16 * mt2 + l15) * 32 + (((4 * ks2 + g) ^ (l15 & 7)) << 2)];
        acc_o[0][mt2] = __builtin_amdgcn_mfma_f32_16x16x32_bf16(af[0], vf, acc_o[0][mt2], 0, 0, 0);
        acc_o[1][mt2] = __builtin_amdgcn_mfma_f32_16x16x32_bf16(af[1], vf, acc_o[1][mt2], 0, 0, 0);
      }
    }

    __syncthreads();     // drains vmcnt (next tile landed) + both waves done with buf
    buf ^= 1;
  }

  // ---- epilogue: reduce l across g-groups, divide, store ----
  #pragma unroll
  for (int qn = 0; qn < 2; ++qn) {
    float lsum = l_part[qn];
    lsum += __shfl_xor(lsum, 16);
    lsum += __shfl_xor(lsum, 32);
    float l4[4];
    #pragma unroll
    for (int rg = 0; rg < 4; ++rg) l4[rg] = __shfl(lsum, 4 * g + rg);
    #pragma unroll
    for (int mt2 = 0; mt2 < 4; ++mt2)
      #pragma unroll
      for (int rg = 0; rg < 4; ++rg) {
        int t = qb + qrow0 + 16 * qn + 4 * g + rg;
        out[((size_t)(b * T_ + t)) * (N_HEADS * HEAD_DIM) + h * HEAD_DIM + 16 * mt2 + l15] =
            acc_o[qn][mt2][rg] / l4[rg];
      }
  }
}

extern "C" void kernel_launch(void* const* d_in, const int* in_sizes, int n_in,
                              void* d_out, int out_size, void* d_ws, size_t ws_size,
                              hipStream_t stream) {
  const float* q   = (const float*)d_in[0];
  const float* k   = (const float*)d_in[1];
  const float* v   = (const float*)d_in[2];
  const float* qw  = (const float*)d_in[3];
  const float* kw  = (const float*)d_in[4];
  const int*   pos = (const int*)d_in[5];

  u32* kp = (u32*)d_ws;                                    // 2.62 MB
  u32* vp = kp + (size_t)B_ * N_KV * NTILES * TILE_U32;    // 2.62 MB
  float* outp = (float*)d_out;

  prep_k_kernel<<<5120, 256, 0, stream>>>(k, kw, pos, kp);
  prep_v_kernel<<<B_ * N_KV * NTILES, 256, 0, stream>>>(v, vp);
  attn_kernel<<<1600, 128, 0, stream>>>(q, qw, pos, kp, vp, outp);
}

// Round 12
// 82.050 us; speedup vs baseline: 1.5631x; 1.5631x over previous
//
#include <hip/hip_runtime.h>
#include <cmath>

typedef float  f32x4  __attribute__((ext_vector_type(4)));
typedef __bf16 bf16x8 __attribute__((ext_vector_type(8)));
typedef unsigned int u32x4 __attribute__((ext_vector_type(4)));
typedef unsigned int   u32;
typedef unsigned short u16;

#define HEAD_DIM 64
#define N_HEADS  25
#define N_KV     5
#define WINDOW   1024
#define N_META   128
#define B_       2
#define T_       2048
#define QB       64
#define NTILES   (T_ / 64)
#define TILE_U32 2048               // 64 rows x 32 u32 (8 KB)

static __device__ __forceinline__ u16 bf16_bits(float f) {
  __bf16 h = (__bf16)f;
  return __builtin_bit_cast(u16, h);
}
static __device__ __forceinline__ u32 pack2(float lo, float hi) {
  return ((u32)bf16_bits(hi) << 16) | bf16_bits(lo);
}
static __device__ __forceinline__ float fexp2(float x) {
  return __builtin_amdgcn_exp2f(x);    // bare v_exp_f32; inputs in [-inf, 0] -> safe
}
static __device__ __forceinline__ void gload16(const u32* g, u32* l) {
  __builtin_amdgcn_global_load_lds((const __attribute__((address_space(1))) u32*)g,
                                   (__attribute__((address_space(3))) u32*)l, 16, 0, 0);
}

// ---------------- Kernel 1: K RMSNorm+RoPE -> bf16 tiles, seg-XOR pre-swizzled ----------
// [b][kvh][tile][key(64)][seg_phys(8) x 4 u32]; seg_phys = seg_log ^ (key&7)
__global__ __launch_bounds__(256) void prep_k_kernel(
    const float* __restrict__ k_in, const float* __restrict__ k_w,
    const int* __restrict__ pos_ids, u32* __restrict__ k_ws)
{
  int gw   = (blockIdx.x * blockDim.x + threadIdx.x) >> 6;
  int lane = threadIdx.x & 63;
  if (gw >= B_ * T_ * N_KV) return;
  int kvh = gw % N_KV;
  int bt  = gw / N_KV;

  float x = k_in[(size_t)bt * (N_KV * HEAD_DIM) + kvh * HEAD_DIM + lane];
  float ss = x * x;
  #pragma unroll
  for (int off = 32; off; off >>= 1) ss += __shfl_xor(ss, off);
  float y = k_w[lane] * x * rsqrtf(ss * (1.f / 64.f) + 1e-6f);

  int   pos = pos_ids[bt];
  float ang = (float)pos * powf(10000.f, -(float)(lane & 31) * (1.f / 32.f));
  float c, s;
  sincosf(ang, &s, &c);              // sincosf(x, sin*, cos*)
  float part = __shfl_xor(y, 32);
  float r = (lane < 32) ? (y * c - part * s) : (y * c + part * s);

  u16 mybits = bf16_bits(r);
  u32 pb = (u32)(u16)__shfl_xor((int)mybits, 1);
  u32 w  = (pb << 16) | mybits;
  int b = bt / T_, t = bt % T_;
  if (!(lane & 1)) {
    int c32 = lane >> 1;
    int kl = t & 63, tile = t >> 6;
    int sp = (c32 >> 2) ^ (kl & 7);
    k_ws[(((size_t)(b * N_KV + kvh) * NTILES + tile)) * TILE_U32 + kl * 32 + sp * 4 + (c32 & 3)] = w;
  }
}

// ---------------- Kernel 1b: V -> bf16 V^T tiles, b128 K-group pre-swizzled ------------
// [b][kvh][tile][d(64)][32 u32]. Logical u32 col c holds keys (2c,2c+1). c = 16a+8b+2g+e
// stored at phys seg sp = (4a+g)^(d&7), slot 2b+e. Attn's b128 read at seg (4ks2+g)^(d&7)
// then yields keys {32ks2+4g+0..3, 32ks2+16+4g+0..3} = exactly the PV A-frag k-order.
__global__ __launch_bounds__(256) void prep_v_kernel(
    const float* __restrict__ v_in, u32* __restrict__ v_ws)
{
  int blk  = blockIdx.x;
  int tile = blk & (NTILES - 1);
  int bk   = blk >> 5;
  int kvh  = bk % N_KV, b = bk / N_KV;
  int t0   = tile * 64;
  int tid  = threadIdx.x;

  __shared__ u16 Tl[64][72];             // [d][key]

  #pragma unroll
  for (int it = 0; it < 4; ++it) {
    int idx = it * 256 + tid;
    int kl = idx >> 4, dq = idx & 15;
    const float4 f = *(const float4*)&v_in[((size_t)(b * T_ + t0 + kl)) * (N_KV * HEAD_DIM) + kvh * HEAD_DIM + dq * 4];
    Tl[dq * 4 + 0][kl] = bf16_bits(f.x);
    Tl[dq * 4 + 1][kl] = bf16_bits(f.y);
    Tl[dq * 4 + 2][kl] = bf16_bits(f.z);
    Tl[dq * 4 + 3][kl] = bf16_bits(f.w);
  }
  __syncthreads();

  u32* outb = v_ws + (size_t)blk * TILE_U32;
  #pragma unroll
  for (int it = 0; it < 8; ++it) {
    int o = it * 256 + tid;
    int d = o >> 5, c = o & 31;
    u32 w = ((u32)Tl[d][2 * c + 1] << 16) | Tl[d][2 * c];
    int a = c >> 4, bs = (c >> 3) & 1, gp = (c >> 1) & 3, e = c & 1;
    int sp = (4 * a + gp) ^ (d & 7);
    outb[d * 32 + sp * 4 + 2 * bs + e] = w;
  }
}

// ---------------- Kernel 2: fused MFMA flash attention (r7 structure) ----------------
__global__ __launch_bounds__(256, 4) void attn_kernel(
    const float* __restrict__ q_in, const float* __restrict__ q_w,
    const int* __restrict__ pos_ids,
    const u32* __restrict__ kws, const u32* __restrict__ vws,
    float* __restrict__ out)
{
  const int blk = blockIdx.x;
  const int r   = blk / 50, v = blk % 50;          // heavy-first: qt descending
  const int qt  = 31 - r;
  const int h   = v % N_HEADS;
  const int b   = v / N_HEADS;
  const int qb  = qt * QB;
  const int kvh = h / (N_HEADS / N_KV);
  const int tid = threadIdx.x, wid = tid >> 6, lane = tid & 63;
  const int l15 = lane & 15, g = lane >> 4;
  const int qrow0 = wid * 16;

  __shared__ u32 Ks[2 * TILE_U32];       // K tiles (buf1 doubles as Q staging pre-loop)
  __shared__ u32 Vt[2 * TILE_U32];       // V^T tiles

  const int nt    = (qt <= 18) ? (qt + 1) : 19;
  const int shift = qt - 18;

  const size_t kvbase = ((size_t)(b * N_KV + kvh)) * NTILES * TILE_U32;
  const u32* kb = kws + kvbase;
  const u32* vb = vws + kvbase;

  // ---- issue tile-0 staging first (hides under Q-staging compute) ----
  #pragma unroll
  for (int j = 0; j < 4; ++j) {
    int ci = (wid << 2) | j;
    if (ci < 8) gload16(kb + ci * 256 + lane * 4, &Ks[ci * 256]);
    else        gload16(vb + (ci - 8) * 256 + lane * 4, &Vt[(ci - 8) * 256]);
  }

  // ---- Q staging into Ks buf1: RMSNorm + RoPE (rotation recurrence); scale 0.125*log2e ----
  {
    const float f = powf(10000.f, -(float)(lane & 31) * (1.f / 32.f));
    const int t0g = b * T_ + qb + qrow0;
    int pos_prev = pos_ids[t0g];
    float cc, sn;
    sincosf((float)pos_prev * f, &sn, &cc);        // sincosf(x, sin*, cos*)
    float sf, cf;
    sincosf(f, &sf, &cf);
    for (int rr = 0; rr < 16; ++rr) {
      if (rr) {
        int pos = pos_ids[t0g + rr];
        if (pos == pos_prev + 1) {                 // wave-uniform fast path
          float c2 = cc * cf - sn * sf;
          sn = sn * cf + cc * sf;
          cc = c2;
        } else {
          sincosf((float)pos * f, &sn, &cc);
        }
        pos_prev = pos;
      }
      float x = q_in[((size_t)(t0g + rr)) * (N_HEADS * HEAD_DIM) + h * HEAD_DIM + lane];
      float ss = x * x;
      #pragma unroll
      for (int off = 32; off; off >>= 1) ss += __shfl_xor(ss, off);
      float y = q_w[lane] * x * rsqrtf(ss * (1.f / 64.f) + 1e-6f);
      float part = __shfl_xor(y, 32);
      float rv = ((lane < 32) ? (y * cc - part * sn) : (y * cc + part * sn)) * 0.18033688f;
      u16 mybits = bf16_bits(rv);
      u32 pb = (u32)(u16)__shfl_xor((int)mybits, 1);
      if (!(lane & 1)) Ks[TILE_U32 + (qrow0 + rr) * 32 + (lane >> 1)] = (pb << 16) | mybits;
    }
  }
  __syncthreads();                       // tile0 loads drained + Q rows visible

  bf16x8 qf[2];
  #pragma unroll
  for (int ks = 0; ks < 2; ++ks)
    qf[ks] = *(const bf16x8*)&Ks[TILE_U32 + (qrow0 + l15) * 32 + 16 * ks + 4 * g];
  __syncthreads();                       // all qf reads done before buf1 is overwritten

  float m_reg = -INFINITY, l_part = 0.f; // l_part: per-lane partial (g-reduce deferred)
  f32x4 acc_o[4];
  #pragma unroll
  for (int mt = 0; mt < 4; ++mt) acc_o[mt] = (f32x4)(0.f);

  const int q_abs = qb + qrow0 + l15;

  int buf = 0;
  for (int i = 0; i < nt; ++i) {
    // ---- prefetch next tile into buf^1 ----
    if (i + 1 < nt) {
      int tn = (qt <= 18 || i + 1 < 2) ? (i + 1) : (i + 1 + shift);
      const u32* kt = kb + (size_t)tn * TILE_U32;
      const u32* vt = vb + (size_t)tn * TILE_U32;
      u32* kd = &Ks[(buf ^ 1) * TILE_U32];
      u32* vd = &Vt[(buf ^ 1) * TILE_U32];
      #pragma unroll
      for (int j = 0; j < 4; ++j) {
        int ci = (wid << 2) | j;
        if (ci < 8) gload16(kt + ci * 256 + lane * 4, kd + ci * 256);
        else        gload16(vt + (ci - 8) * 256 + lane * 4, vd + (ci - 8) * 256);
      }
    }
    const int k0 = ((qt <= 18 || i < 2) ? i : i + shift) << 6;

    // ---- S^T = K·Q^T (C: col=l15=q, row=key 16mt+4g+rg) ----
    f32x4 accs[4];
    #pragma unroll
    for (int mt = 0; mt < 4; ++mt) accs[mt] = (f32x4)(0.f);
    #pragma unroll
    for (int ks = 0; ks < 2; ++ks) {
      #pragma unroll
      for (int mt = 0; mt < 4; ++mt) {
        bf16x8 kf = *(const bf16x8*)&Ks[buf * TILE_U32 + (16 * mt + l15) * 32 + (((4 * ks + g) ^ (l15 & 7)) << 2)];
        accs[mt] = __builtin_amdgcn_mfma_f32_16x16x32_bf16(kf, qf[ks], accs[mt], 0, 0, 0);
      }
    }

    // ---- mask only on boundary tiles (diagonal; window-entry i==2 when qt>=18) ----
    const bool do_mask = (i == nt - 1) || (qt >= 18 && i == 2);
    float tmax = -INFINITY;
    if (do_mask) {
      #pragma unroll
      for (int mt = 0; mt < 4; ++mt)
        #pragma unroll
        for (int rg = 0; rg < 4; ++rg) {
          int key = k0 + 16 * mt + 4 * g + rg;
          bool ok = (key <= q_abs) && ((key >= q_abs - (WINDOW - 1)) || (key < N_META));
          float sv = ok ? accs[mt][rg] : -INFINITY;
          accs[mt][rg] = sv;
          tmax = fmaxf(tmax, sv);
        }
    } else {
      #pragma unroll
      for (int mt = 0; mt < 4; ++mt)
        #pragma unroll
        for (int rg = 0; rg < 4; ++rg) tmax = fmaxf(tmax, accs[mt][rg]);
    }
    tmax = fmaxf(tmax, __shfl_xor(tmax, 16));
    tmax = fmaxf(tmax, __shfl_xor(tmax, 32));

    // ---- online softmax (exp2 domain, raw v_exp_f32) with defer-skip ----
    float mn = m_reg;
    if (!__all(tmax <= m_reg)) {
      mn = fmaxf(m_reg, tmax);
      float scl = fexp2(m_reg - mn);
      m_reg = mn;
      l_part *= scl;
      float scl4[4];
      #pragma unroll
      for (int rg = 0; rg < 4; ++rg) scl4[rg] = __shfl(scl, 4 * g + rg);
      #pragma unroll
      for (int mt2 = 0; mt2 < 4; ++mt2)
        #pragma unroll
        for (int rg = 0; rg < 4; ++rg) acc_o[mt2][rg] *= scl4[rg];
    }
    float rsum = 0.f;
    #pragma unroll
    for (int mt = 0; mt < 4; ++mt)
      #pragma unroll
      for (int rg = 0; rg < 4; ++rg) {
        float pi = fexp2(accs[mt][rg] - mn);    // v_exp_f32(-inf) = 0
        accs[mt][rg] = pi;
        rsum += pi;
      }
    l_part += rsum;                      // per-lane partial; reduce in epilogue

    // ---- O += P·V, P in-register (permuted-K mfma; V b128 in matching order) ----
    #pragma unroll
    for (int ks2 = 0; ks2 < 2; ++ks2) {
      const int m0 = 2 * ks2, m1 = 2 * ks2 + 1;
      u32x4 aw;
      aw.x = pack2(accs[m0][0], accs[m0][1]);
      aw.y = pack2(accs[m0][2], accs[m0][3]);
      aw.z = pack2(accs[m1][0], accs[m1][1]);
      aw.w = pack2(accs[m1][2], accs[m1][3]);
      bf16x8 af = __builtin_bit_cast(bf16x8, aw);
      #pragma unroll
      for (int mt2 = 0; mt2 < 4; ++mt2) {
        bf16x8 vf = *(const bf16x8*)&Vt[buf * TILE_U32 + (16 * mt2 + l15) * 32 + (((4 * ks2 + g) ^ (l15 & 7)) << 2)];
        acc_o[mt2] = __builtin_amdgcn_mfma_f32_16x16x32_bf16(af, vf, acc_o[mt2], 0, 0, 0);
      }
    }

    __syncthreads();     // drains vmcnt (next tile landed) + all waves done with buf
    buf ^= 1;
  }

  // ---- epilogue: reduce l across g-groups once, divide, store ----
  float lsum = l_part;
  lsum += __shfl_xor(lsum, 16);
  lsum += __shfl_xor(lsum, 32);
  float l4[4];
  #pragma unroll
  for (int rg = 0; rg < 4; ++rg) l4[rg] = __shfl(lsum, 4 * g + rg);
  #pragma unroll
  for (int mt2 = 0; mt2 < 4; ++mt2)
    #pragma unroll
    for (int rg = 0; rg < 4; ++rg) {
      int t = qb + qrow0 + 4 * g + rg;
      out[((size_t)(b * T_ + t)) * (N_HEADS * HEAD_DIM) + h * HEAD_DIM + 16 * mt2 + l15] =
          acc_o[mt2][rg] / l4[rg];
    }
}

extern "C" void kernel_launch(void* const* d_in, const int* in_sizes, int n_in,
                              void* d_out, int out_size, void* d_ws, size_t ws_size,
                              hipStream_t stream) {
  const float* q   = (const float*)d_in[0];
  const float* k   = (const float*)d_in[1];
  const float* v   = (const float*)d_in[2];
  const float* qw  = (const float*)d_in[3];
  const float* kw  = (const float*)d_in[4];
  const int*   pos = (const int*)d_in[5];

  u32* kp = (u32*)d_ws;                                    // 2.62 MB
  u32* vp = kp + (size_t)B_ * N_KV * NTILES * TILE_U32;    // 2.62 MB
  float* outp = (float*)d_out;

  prep_k_kernel<<<5120, 256, 0, stream>>>(k, kw, pos, kp);
  prep_v_kernel<<<B_ * N_KV * NTILES, 256, 0, stream>>>(v, vp);
  attn_kernel<<<1600, 256, 0, stream>>>(q, qw, pos, kp, vp, outp);
}